// Round 11
// baseline (624.599 us; speedup 1.0000x reference)
//
#include <hip/hip_runtime.h>

#define N_NODES 100000
#define N_EDGES 1600000
#define D 128
#define N_GRAPHS 64
#define BN_EPS 1e-5f
#define NSLICE 16

// dst-buckets for the two-phase scatter
#define BNODES 256
#define NBUCK ((N_NODES + BNODES - 1) / BNODES)  // 391
#define EPB 8192
#define NABLK ((N_EDGES + EPB - 1) / EPB)        // 196

typedef short short8 __attribute__((ext_vector_type(8)));
typedef float f32x4 __attribute__((ext_vector_type(4)));

__device__ inline unsigned short f2bf(float f) {
  unsigned int u = __float_as_uint(f);
  u += 0x7fffu + ((u >> 16) & 1);
  return (unsigned short)(u >> 16);
}
__device__ inline float bf2f(unsigned short h) {
  return __uint_as_float(((unsigned int)h) << 16);
}
__device__ inline void unpack8(uint4 u, float* f) {
  f[0] = __uint_as_float(u.x << 16); f[1] = __uint_as_float(u.x & 0xffff0000u);
  f[2] = __uint_as_float(u.y << 16); f[3] = __uint_as_float(u.y & 0xffff0000u);
  f[4] = __uint_as_float(u.z << 16); f[5] = __uint_as_float(u.z & 0xffff0000u);
  f[6] = __uint_as_float(u.w << 16); f[7] = __uint_as_float(u.w & 0xffff0000u);
}
__device__ inline uint4 pack8(const float* f) {
  uint4 u;
  u.x = f2bf(f[0]) | ((unsigned)f2bf(f[1]) << 16);
  u.y = f2bf(f[2]) | ((unsigned)f2bf(f[3]) << 16);
  u.z = f2bf(f[4]) | ((unsigned)f2bf(f[5]) << 16);
  u.w = f2bf(f[6]) | ((unsigned)f2bf(f[7]) << 16);
  return u;
}

// ---------------- input casts / weight prep ----------------
__global__ __launch_bounds__(256) void k_cast(const float* __restrict__ in,
                                              unsigned short* __restrict__ o) {
  long i = ((long)blockIdx.x * blockDim.x + threadIdx.x) * 8;
  if (i >= (long)N_NODES * D) return;
  float4 a = *(const float4*)(in + i);
  float4 b = *(const float4*)(in + i + 4);
  float f[8] = {a.x, a.y, a.z, a.w, b.x, b.y, b.z, b.w};
  *(uint4*)(o + i) = pack8(f);
}

// Wt[mat][n][k] = bf16(W[mat][k][n]); mat = layer*2 + (0:W1,1:W2)
__global__ __launch_bounds__(128) void k_wprep(const float* __restrict__ W1,
                                               const float* __restrict__ W2,
                                               unsigned short* __restrict__ Wt) {
  int m = blockIdx.x;
  int n = blockIdx.y;
  int k = threadIdx.x;
  int l = m >> 1, s = m & 1;
  const float* W = (s == 0 ? W1 : W2) + (size_t)l * D * D;
  Wt[((size_t)m * D + n) * D + k] = f2bf(W[(size_t)k * D + n]);
}

// ---------------- bucket histogram + scan ----------------
__global__ __launch_bounds__(256) void k_histb(const int* __restrict__ dst,
                                               int* __restrict__ ecount) {
  __shared__ int lh[NBUCK];
  const int t = threadIdx.x;
  const int e0 = blockIdx.x * EPB;
  const int e1 = min(e0 + EPB, N_EDGES);
  for (int i = t; i < NBUCK; i += 256) lh[i] = 0;
  __syncthreads();
  for (int e = e0 + t; e < e1; e += 256) atomicAdd(&lh[dst[e] >> 8], 1);
  __syncthreads();
  for (int i = t; i < NBUCK; i += 256)
    if (lh[i]) atomicAdd(&ecount[i], lh[i]);
}

__global__ __launch_bounds__(512) void k_scanb(const int* __restrict__ ecount,
                                               int* __restrict__ ebase,
                                               int* __restrict__ gcur) {
  __shared__ int ls[512];
  int t = threadIdx.x;
  int v = (t < NBUCK) ? ecount[t] : 0;
  ls[t] = v;
  __syncthreads();
  for (int o = 1; o < 512; o <<= 1) {
    int u = (t >= o) ? ls[t - o] : 0;
    __syncthreads();
    ls[t] += u;
    __syncthreads();
  }
  int ex = ls[t] - v;
  if (t < NBUCK) { ebase[t] = ex; gcur[t] = ex; }
  if (t == 0) ebase[NBUCK] = N_EDGES;
}

// ---------------- two-phase bucketed edge scatter ----------------
__global__ __launch_bounds__(256) void k_scatA(const int* __restrict__ ei,
                                               int* __restrict__ gcur,
                                               int2* __restrict__ pairs) {
  __shared__ int lh[NBUCK];
  __shared__ int lbase[NBUCK];
  const int t = threadIdx.x;
  const int e0 = blockIdx.x * EPB;
  const int e1 = min(e0 + EPB, N_EDGES);
  for (int i = t; i < NBUCK; i += 256) lh[i] = 0;
  __syncthreads();
  for (int e = e0 + t; e < e1; e += 256) atomicAdd(&lh[ei[N_EDGES + e] >> 8], 1);
  __syncthreads();
  for (int i = t; i < NBUCK; i += 256)
    lbase[i] = (lh[i] > 0) ? atomicAdd(&gcur[i], lh[i]) : 0;
  __syncthreads();
  for (int e = e0 + t; e < e1; e += 256) {
    int s = ei[e];
    int d = ei[N_EDGES + e];
    int p = atomicAdd(&lbase[d >> 8], 1);
    pairs[p] = make_int2(s, d);
  }
}

// Phase B: per bucket, build per-node CSR offsets in LDS and place srcs.
// esrc stores BYTE offsets (src * 256) — consumed by k_aggz.
__global__ __launch_bounds__(256) void k_scatB(const int2* __restrict__ pairs,
                                               const int* __restrict__ ebase,
                                               int* __restrict__ off,
                                               int* __restrict__ esrc) {
  __shared__ int lcnt[BNODES];
  __shared__ int ls[256];
  const int t = threadIdx.x;
  const int b = blockIdx.x;
  const int nb0 = b * BNODES;
  const int nn = min(BNODES, N_NODES - nb0);
  const int s0 = ebase[b], s1 = ebase[b + 1];
  if (t < nn) lcnt[t] = 0;
  __syncthreads();
  for (int e = s0 + t; e < s1; e += 256) atomicAdd(&lcnt[pairs[e].y - nb0], 1);
  __syncthreads();
  int c0 = (t < nn) ? lcnt[t] : 0;
  ls[t] = c0;
  __syncthreads();
  for (int o = 1; o < 256; o <<= 1) {
    int u = (t >= o) ? ls[t - o] : 0;
    __syncthreads();
    ls[t] += u;
    __syncthreads();
  }
  int pre = ls[t] - c0;  // exclusive prefix within bucket
  if (t < nn) {
    off[nb0 + t] = s0 + pre;
    lcnt[t] = s0 + pre;  // reuse as cursor
  }
  __syncthreads();
  for (int e = s0 + t; e < s1; e += 256) {
    int2 p = pairs[e];
    int pos = atomicAdd(&lcnt[p.y - nb0], 1);
    esrc[pos] = p.x << 8;  // byte offset of the 256B bf16 row
  }
  if (b == 0 && t == 0) off[N_NODES] = N_EDGES;
}

// ---------------- agg + (1+eps)*h: ONE WAVE PER NODE, 2 feats/lane ----------
// R3-measured-best form (65.4us): 4B/lane, 8-edge unroll; byte-offset esrc.
// At the fabric-BW roofline: 410MB logical / 65us = 6.3 TB/s (R9 measured).
// MODE 1 applies h' = relu(y*sc + tb) to every gathered row on the fly.
template <int MODE>
__global__ __launch_bounds__(256) void k_aggz(const unsigned short* __restrict__ h,
                                              const int* __restrict__ off,
                                              const int* __restrict__ esrcB,
                                              const float* __restrict__ epsp,
                                              const float* __restrict__ sc,
                                              const float* __restrict__ tb,
                                              unsigned short* __restrict__ z) {
  const int lane = threadIdx.x & 63;
  const int n = blockIdx.x * 4 + (threadIdx.x >> 6);
  const int c = lane << 1;
  const int cb = lane << 2;  // byte offset of the 2 shorts
  const char* hb = (const char*)h;
  float S0 = 0.f, S1 = 0.f, T0 = 0.f, T1 = 0.f;
  if (MODE == 1) { S0 = sc[c]; S1 = sc[c + 1]; T0 = tb[c]; T1 = tb[c + 1]; }
  const float e = 1.0f + epsp[0];
  const int o0 = off[n], o1 = off[n + 1];

  float a0, a1;
  {
    unsigned int u = *(const unsigned int*)(hb + (size_t)n * 256 + cb);
    float lo = __uint_as_float(u << 16);
    float hi = __uint_as_float(u & 0xffff0000u);
    if (MODE == 1) {
      lo = fmaxf(fmaf(lo, S0, T0), 0.f);
      hi = fmaxf(fmaf(hi, S1, T1), 0.f);
    }
    a0 = e * lo;
    a1 = e * hi;
  }

  int j = o0;
  for (; j + 7 < o1; j += 8) {
    int b0 = esrcB[j], b1 = esrcB[j + 1], b2 = esrcB[j + 2], b3 = esrcB[j + 3];
    int b4 = esrcB[j + 4], b5 = esrcB[j + 5], b6 = esrcB[j + 6], b7 = esrcB[j + 7];
    unsigned int u0 = *(const unsigned int*)(hb + (unsigned)b0 + cb);
    unsigned int u1 = *(const unsigned int*)(hb + (unsigned)b1 + cb);
    unsigned int u2 = *(const unsigned int*)(hb + (unsigned)b2 + cb);
    unsigned int u3 = *(const unsigned int*)(hb + (unsigned)b3 + cb);
    unsigned int u4 = *(const unsigned int*)(hb + (unsigned)b4 + cb);
    unsigned int u5 = *(const unsigned int*)(hb + (unsigned)b5 + cb);
    unsigned int u6 = *(const unsigned int*)(hb + (unsigned)b6 + cb);
    unsigned int u7 = *(const unsigned int*)(hb + (unsigned)b7 + cb);
    float l0 = __uint_as_float(u0 << 16), h0 = __uint_as_float(u0 & 0xffff0000u);
    float l1 = __uint_as_float(u1 << 16), h1 = __uint_as_float(u1 & 0xffff0000u);
    float l2 = __uint_as_float(u2 << 16), h2 = __uint_as_float(u2 & 0xffff0000u);
    float l3 = __uint_as_float(u3 << 16), h3 = __uint_as_float(u3 & 0xffff0000u);
    float l4 = __uint_as_float(u4 << 16), h4 = __uint_as_float(u4 & 0xffff0000u);
    float l5 = __uint_as_float(u5 << 16), h5 = __uint_as_float(u5 & 0xffff0000u);
    float l6 = __uint_as_float(u6 << 16), h6 = __uint_as_float(u6 & 0xffff0000u);
    float l7 = __uint_as_float(u7 << 16), h7 = __uint_as_float(u7 & 0xffff0000u);
    if (MODE == 1) {
      l0 = fmaxf(fmaf(l0, S0, T0), 0.f); h0 = fmaxf(fmaf(h0, S1, T1), 0.f);
      l1 = fmaxf(fmaf(l1, S0, T0), 0.f); h1 = fmaxf(fmaf(h1, S1, T1), 0.f);
      l2 = fmaxf(fmaf(l2, S0, T0), 0.f); h2 = fmaxf(fmaf(h2, S1, T1), 0.f);
      l3 = fmaxf(fmaf(l3, S0, T0), 0.f); h3 = fmaxf(fmaf(h3, S1, T1), 0.f);
      l4 = fmaxf(fmaf(l4, S0, T0), 0.f); h4 = fmaxf(fmaf(h4, S1, T1), 0.f);
      l5 = fmaxf(fmaf(l5, S0, T0), 0.f); h5 = fmaxf(fmaf(h5, S1, T1), 0.f);
      l6 = fmaxf(fmaf(l6, S0, T0), 0.f); h6 = fmaxf(fmaf(h6, S1, T1), 0.f);
      l7 = fmaxf(fmaf(l7, S0, T0), 0.f); h7 = fmaxf(fmaf(h7, S1, T1), 0.f);
    }
    a0 += ((l0 + l1) + (l2 + l3)) + ((l4 + l5) + (l6 + l7));
    a1 += ((h0 + h1) + (h2 + h3)) + ((h4 + h5) + (h6 + h7));
  }
  for (; j + 3 < o1; j += 4) {
    int b0 = esrcB[j], b1 = esrcB[j + 1], b2 = esrcB[j + 2], b3 = esrcB[j + 3];
    unsigned int u0 = *(const unsigned int*)(hb + (unsigned)b0 + cb);
    unsigned int u1 = *(const unsigned int*)(hb + (unsigned)b1 + cb);
    unsigned int u2 = *(const unsigned int*)(hb + (unsigned)b2 + cb);
    unsigned int u3 = *(const unsigned int*)(hb + (unsigned)b3 + cb);
    float l0 = __uint_as_float(u0 << 16), h0 = __uint_as_float(u0 & 0xffff0000u);
    float l1 = __uint_as_float(u1 << 16), h1 = __uint_as_float(u1 & 0xffff0000u);
    float l2 = __uint_as_float(u2 << 16), h2 = __uint_as_float(u2 & 0xffff0000u);
    float l3 = __uint_as_float(u3 << 16), h3 = __uint_as_float(u3 & 0xffff0000u);
    if (MODE == 1) {
      l0 = fmaxf(fmaf(l0, S0, T0), 0.f); h0 = fmaxf(fmaf(h0, S1, T1), 0.f);
      l1 = fmaxf(fmaf(l1, S0, T0), 0.f); h1 = fmaxf(fmaf(h1, S1, T1), 0.f);
      l2 = fmaxf(fmaf(l2, S0, T0), 0.f); h2 = fmaxf(fmaf(h2, S1, T1), 0.f);
      l3 = fmaxf(fmaf(l3, S0, T0), 0.f); h3 = fmaxf(fmaf(h3, S1, T1), 0.f);
    }
    a0 += (l0 + l1) + (l2 + l3);
    a1 += (h0 + h1) + (h2 + h3);
  }
  for (; j < o1; j++) {
    unsigned int u0 = *(const unsigned int*)(hb + (unsigned)esrcB[j] + cb);
    float l0 = __uint_as_float(u0 << 16), h0 = __uint_as_float(u0 & 0xffff0000u);
    if (MODE == 1) {
      l0 = fmaxf(fmaf(l0, S0, T0), 0.f);
      h0 = fmaxf(fmaf(h0, S1, T1), 0.f);
    }
    a0 += l0;
    a1 += h0;
  }
  unsigned int pk = (unsigned int)f2bf(a0) | ((unsigned int)f2bf(a1) << 16);
  *(unsigned int*)((char*)z + (size_t)n * 256 + cb) = pk;
}

// ---------------- MFMA GEMM + fused BN column stats ----------------
// 128 rows/block, 512 threads (8 waves): halves block count (782) and Ws
// re-staging; 70.7KB LDS -> 2 blocks/CU = 16 waves/CU.
// C-store: DIRECT per-element global stores (R9 form). The R10 in-LDS
// transpose store (ds_write_b16 scatter -> ds_read_b128 readback, no barrier)
// intermittently corrupted outputs — banned: do not rely on within-wave
// mixed-width LDS RAW ordering for C-stores.
// MODE=1: A-rows transformed by relu(bn(.)) with coefs folded inline.
template <int MODE>
__global__ __launch_bounds__(512) void k_gemm(const unsigned short* __restrict__ A,
                                              const unsigned short* __restrict__ Wt,
                                              unsigned short* __restrict__ out,
                                              const float* __restrict__ psA,
                                              const float* __restrict__ pqA,
                                              const float* __restrict__ gamA,
                                              const float* __restrict__ betA,
                                              float* __restrict__ ssum,
                                              float* __restrict__ ssq) {
  __shared__ unsigned short Zs[128 * 136];
  __shared__ unsigned short Ws[128 * 136];
  __shared__ float scL[128];
  __shared__ float tbL[128];
  const int t = threadIdx.x;
  const int row0 = blockIdx.x * 128;

  // stage Wt first: loads independent of the BN fold -> overlap latency
#pragma unroll
  for (int i = 0; i < 4; i++) {
    int q = t + i * 512;  // 0..2047: 128 rows x 16 col-blocks
    int r = q >> 4, cbw = (q & 15) << 3;
    *(uint4*)&Ws[r * 136 + cbw] = *(const uint4*)(Wt + (size_t)r * D + cbw);
  }

  if constexpr (MODE == 1) {
    if (t < 128) {
      float S = 0.f, Q = 0.f;
#pragma unroll
      for (int i = 0; i < NSLICE; i++) { S += psA[i * 128 + t]; Q += pqA[i * 128 + t]; }
      float m = S * (1.0f / (float)N_NODES);
      float v = Q * (1.0f / (float)N_NODES) - m * m;
      float r = rsqrtf(v + BN_EPS);
      float s = r * gamA[t];
      scL[t] = s;
      tbL[t] = betA[t] - m * s;
    }
    __syncthreads();  // scL/tbL ready before A transform
  }

#pragma unroll
  for (int i = 0; i < 4; i++) {
    int q = t + i * 512;  // 0..2047: 128 rows x 16 col-blocks
    int r = q >> 4, cb = (q & 15) << 3;
    int grow = row0 + r;
    uint4 u = make_uint4(0u, 0u, 0u, 0u);
    if (grow < N_NODES) {
      u = *(const uint4*)(A + (size_t)grow * D + cb);
      if constexpr (MODE == 1) {
        float f[8];
        unpack8(u, f);
#pragma unroll
        for (int jj = 0; jj < 8; jj++)
          f[jj] = fmaxf(fmaf(f[jj], scL[cb + jj], tbL[cb + jj]), 0.f);
        u = pack8(f);
      }
    }
    *(uint4*)&Zs[r * 136 + cb] = u;
  }
  __syncthreads();

  const int lane = t & 63;
  const int wave = t >> 6;       // 0..7
  const int quad = lane >> 4;
  const int lr = lane & 15;
  const int m0 = wave * 16;      // wave's private 16-row stripe

  f32x4 acc[8];
#pragma unroll
  for (int i = 0; i < 8; i++) acc[i] = (f32x4){0.f, 0.f, 0.f, 0.f};

#pragma unroll
  for (int kc = 0; kc < 128; kc += 32) {
    short8 af = *(const short8*)&Zs[(m0 + lr) * 136 + kc + quad * 8];
#pragma unroll
    for (int nt = 0; nt < 8; nt++) {
      short8 bf = *(const short8*)&Ws[(nt * 16 + lr) * 136 + kc + quad * 8];
      acc[nt] = __builtin_amdgcn_mfma_f32_16x16x32_bf16(af, bf, acc[nt], 0, 0, 0);
    }
  }

  // column stats: per-quad sums -> cross-quad shfl reduce -> direct atomics
  const int slice = blockIdx.x & (NSLICE - 1);
#pragma unroll
  for (int nt = 0; nt < 8; nt++) {
    float s = acc[nt][0] + acc[nt][1] + acc[nt][2] + acc[nt][3];
    float qq = acc[nt][0] * acc[nt][0] + acc[nt][1] * acc[nt][1] +
               acc[nt][2] * acc[nt][2] + acc[nt][3] * acc[nt][3];
    s += __shfl_xor(s, 16);
    s += __shfl_xor(s, 32);
    qq += __shfl_xor(qq, 16);
    qq += __shfl_xor(qq, 32);
    if (quad == 0) {
      atomicAdd(&ssum[slice * 128 + nt * 16 + lr], s);
      atomicAdd(&ssq[slice * 128 + nt * 16 + lr], qq);
    }
  }

  // direct C-store (proven-safe R9 form)
#pragma unroll
  for (int rr = 0; rr < 4; rr++) {
    int grow = row0 + m0 + quad * 4 + rr;
    if (grow < N_NODES) {
#pragma unroll
      for (int nt = 0; nt < 8; nt++)
        out[(size_t)grow * D + nt * 16 + lr] = f2bf(acc[nt][rr]);
    }
  }
}

// fold stats -> affine BN coeffs: bn(y) = y*sc + tb (for the 25000-block aggz
// consumer; 1-block launch is ~3us — NEVER a per-block __threadfence fold,
// which forces cross-XCD L2 writebacks (~220us, measured round 4))
__global__ void k_bnfin(const float* __restrict__ ssum, const float* __restrict__ ssq,
                        const float* __restrict__ gamma, const float* __restrict__ beta,
                        float* __restrict__ sc, float* __restrict__ tb) {
  int f = threadIdx.x;
  float S = 0.f, Q = 0.f;
  for (int i = 0; i < NSLICE; i++) { S += ssum[i * 128 + f]; Q += ssq[i * 128 + f]; }
  float m = S * (1.0f / (float)N_NODES);
  float v = Q * (1.0f / (float)N_NODES) - m * m;
  float r = rsqrtf(v + BN_EPS);
  float s = r * gamma[f];
  sc[f] = s;
  tb[f] = beta[f] - m * s;
}

// ---------------- fused BN2+ReLU + node_emb write + graph readout ------------
#define RCH 64
__global__ __launch_bounds__(128) void k_readout(const unsigned short* __restrict__ y,
                                                 const int* __restrict__ batch,
                                                 const float* __restrict__ psA,
                                                 const float* __restrict__ pqA,
                                                 const float* __restrict__ gam,
                                                 const float* __restrict__ bet,
                                                 float* __restrict__ node_out,
                                                 float* __restrict__ gsum,
                                                 int* __restrict__ gcnt) {
  int start = blockIdx.x * RCH;
  int end = min(start + RCH, N_NODES);
  if (start >= end) return;
  int f = threadIdx.x;
  // inline BN-coef fold
  float S = 0.f, Q = 0.f;
#pragma unroll
  for (int i = 0; i < NSLICE; i++) { S += psA[i * 128 + f]; Q += pqA[i * 128 + f]; }
  float m = S * (1.0f / (float)N_NODES);
  float v = Q * (1.0f / (float)N_NODES) - m * m;
  float r = rsqrtf(v + BN_EPS);
  float s = r * gam[f];
  float tt = bet[f] - m * s;

  float acc = 0.f;
  int cnt = 0;
  int curg = batch[start];
  for (int n = start; n < end; n++) {
    int gg = batch[n];
    float vv = fmaxf(fmaf(bf2f(y[(size_t)n * D + f]), s, tt), 0.f);
    node_out[(size_t)n * D + f] = vv;
    if (gg != curg) {
      atomicAdd(&gsum[curg * D + f], acc);
      if (f == 0) atomicAdd(&gcnt[curg], cnt);
      acc = 0.f; cnt = 0; curg = gg;
    }
    acc += vv;
    cnt++;
  }
  atomicAdd(&gsum[curg * D + f], acc);
  if (f == 0) atomicAdd(&gcnt[curg], cnt);
}

__global__ __launch_bounds__(128) void k_gnorm(const float* __restrict__ gsum,
                                               const int* __restrict__ gcnt,
                                               float* __restrict__ out) {
  __shared__ float red[128];
  int g = blockIdx.x, f = threadIdx.x;
  float c = (float)gcnt[g];
  float v = gsum[g * D + f] / fmaxf(c, 1.0f);
  red[f] = v * v;
  __syncthreads();
  for (int o = 64; o > 0; o >>= 1) {
    if (f < o) red[f] += red[f + o];
    __syncthreads();
  }
  float nrm = sqrtf(red[0]);
  out[(size_t)g * D + f] = v / fmaxf(nrm, 1e-12f);
}

extern "C" void kernel_launch(void* const* d_in, const int* in_sizes, int n_in,
                              void* d_out, int out_size, void* d_ws, size_t ws_size,
                              hipStream_t stream) {
  const float* x   = (const float*)d_in[0];
  const int*   ei  = (const int*)d_in[1];
  const int*   bat = (const int*)d_in[2];
  const float* W1  = (const float*)d_in[3];
  const float* g1  = (const float*)d_in[4];
  const float* b1  = (const float*)d_in[5];
  const float* W2  = (const float*)d_in[6];
  const float* g2  = (const float*)d_in[7];
  const float* b2  = (const float*)d_in[8];
  const float* eps = (const float*)d_in[9];
  float* out = (float*)d_out;

  char* w = (char*)d_ws;
  const size_t FEAT_B = (size_t)N_NODES * D * 2;
  unsigned short* xb   = (unsigned short*)w; w += FEAT_B;
  unsigned short* bufA = (unsigned short*)w; w += FEAT_B;  // also aliases pairs
  unsigned short* bufB = (unsigned short*)w; w += FEAT_B;
  unsigned short* bufC = (unsigned short*)w; w += FEAT_B;
  unsigned short* WtB  = (unsigned short*)w; w += (size_t)6 * D * D * 2;
  int* off   = (int*)w; w += 400016;
  int* ebase = (int*)w; w += 2048;
  int* gcur  = (int*)w; w += 2048;
  int* esrc  = (int*)w; w += (size_t)N_EDGES * 4;
  float* sc2 = (float*)w; w += 512;
  float* tb2 = (float*)w; w += 512;
  // zero-init region (single memset): ecount | stats | gsum | gcnt
  char* zreg = w;
  int* ecount  = (int*)w; w += 2048;
  float* stats = (float*)w; w += (size_t)6 * 2 * NSLICE * 128 * 4;  // 96 KB
  float* gsum  = (float*)w; w += (size_t)N_GRAPHS * D * 4;
  int* gcnt    = (int*)w; w += 256;
  size_t zbytes = (size_t)((char*)w - zreg);
  // pairs (12.8 MB) aliases bufA (25.6 MB): pairs consumed by k_scatB before
  // the first k_aggz writes bufA (single-stream serialization).
  int2* pairs = (int2*)bufA;

  hipMemsetAsync(zreg, 0, zbytes, stream);

  k_cast<<<(N_NODES * D / 8 + 255) / 256, 256, 0, stream>>>(x, xb);
  k_wprep<<<dim3(6, 128), 128, 0, stream>>>(W1, W2, WtB);

  k_histb<<<NABLK, 256, 0, stream>>>(ei + N_EDGES, ecount);
  k_scanb<<<1, 512, 0, stream>>>(ecount, ebase, gcur);
  k_scatA<<<NABLK, 256, 0, stream>>>(ei, gcur, pairs);
  k_scatB<<<NBUCK, 256, 0, stream>>>(pairs, ebase, off, esrc);

  const int gemm_grid = (N_NODES + 127) / 128;  // 782
  const int aggz_grid = N_NODES / 4;            // 25000 exactly

  for (int l = 0; l < 3; l++) {
    float* s1 = stats + (size_t)(l * 2 + 0) * 2 * NSLICE * 128;
    float* q1 = s1 + NSLICE * 128;
    float* s2 = stats + (size_t)(l * 2 + 1) * 2 * NSLICE * 128;
    float* q2 = s2 + NSLICE * 128;
    const unsigned short* Wa = WtB + (size_t)(l * 2 + 0) * D * D;
    const unsigned short* Wb = WtB + (size_t)(l * 2 + 1) * D * D;
    if (l == 0) {
      k_aggz<0><<<aggz_grid, 256, 0, stream>>>(xb, off, esrc, eps + l,
                                               nullptr, nullptr, bufA);
    } else {
      k_aggz<1><<<aggz_grid, 256, 0, stream>>>(bufC, off, esrc, eps + l,
                                               sc2, tb2, bufA);
    }
    // y1 = z @ W1 (+ stats)
    k_gemm<0><<<gemm_grid, 512, 0, stream>>>(bufA, Wa, bufB,
                                             nullptr, nullptr, nullptr, nullptr,
                                             s1, q1);
    // y2 = relu(bn1(y1)) @ W2 (+ stats), bn1 coefs folded inline
    k_gemm<1><<<gemm_grid, 512, 0, stream>>>(bufB, Wb, bufC,
                                             s1, q1, g1 + (size_t)l * D, b1 + (size_t)l * D,
                                             s2, q2);
    // bn2 coefs for the next layer's aggz (25000-block consumer: fold once here)
    if (l < 2) {
      k_bnfin<<<1, 128, 0, stream>>>(s2, q2, g2 + (size_t)l * D, b2 + (size_t)l * D,
                                     sc2, tb2);
    }
  }

  float* ps2f = stats + (size_t)(2 * 2 + 1) * 2 * NSLICE * 128;
  float* pq2f = ps2f + NSLICE * 128;
  k_readout<<<(N_NODES + RCH - 1) / RCH, 128, 0, stream>>>(
      bufC, bat, ps2f, pq2f, g2 + (size_t)2 * D, b2 + (size_t)2 * D,
      out, gsum, gcnt);
  k_gnorm<<<N_GRAPHS, 128, 0, stream>>>(gsum, gcnt, out + (size_t)N_NODES * D);
}

// Round 16
// 615.842 us; speedup vs baseline: 1.0142x; 1.0142x over previous
//
#include <hip/hip_runtime.h>

#define N_NODES 100000
#define N_EDGES 1600000
#define D 128
#define N_GRAPHS 64
#define BN_EPS 1e-5f
#define NSLICE 16

// dst-buckets for the two-phase scatter
#define BNODES 256
#define NBUCK ((N_NODES + BNODES - 1) / BNODES)  // 391
#define EPB 8192
#define NABLK ((N_EDGES + EPB - 1) / EPB)        // 196

typedef short short8 __attribute__((ext_vector_type(8)));
typedef float f32x4 __attribute__((ext_vector_type(4)));

__device__ inline unsigned short f2bf(float f) {
  unsigned int u = __float_as_uint(f);
  u += 0x7fffu + ((u >> 16) & 1);
  return (unsigned short)(u >> 16);
}
__device__ inline float bf2f(unsigned short h) {
  return __uint_as_float(((unsigned int)h) << 16);
}
__device__ inline void unpack8(uint4 u, float* f) {
  f[0] = __uint_as_float(u.x << 16); f[1] = __uint_as_float(u.x & 0xffff0000u);
  f[2] = __uint_as_float(u.y << 16); f[3] = __uint_as_float(u.y & 0xffff0000u);
  f[4] = __uint_as_float(u.z << 16); f[5] = __uint_as_float(u.z & 0xffff0000u);
  f[6] = __uint_as_float(u.w << 16); f[7] = __uint_as_float(u.w & 0xffff0000u);
}
__device__ inline uint4 pack8(const float* f) {
  uint4 u;
  u.x = f2bf(f[0]) | ((unsigned)f2bf(f[1]) << 16);
  u.y = f2bf(f[2]) | ((unsigned)f2bf(f[3]) << 16);
  u.z = f2bf(f[4]) | ((unsigned)f2bf(f[5]) << 16);
  u.w = f2bf(f[6]) | ((unsigned)f2bf(f[7]) << 16);
  return u;
}

// ---------------- input casts / weight prep ----------------
__global__ __launch_bounds__(256) void k_cast(const float* __restrict__ in,
                                              unsigned short* __restrict__ o) {
  long i = ((long)blockIdx.x * blockDim.x + threadIdx.x) * 8;
  if (i >= (long)N_NODES * D) return;
  float4 a = *(const float4*)(in + i);
  float4 b = *(const float4*)(in + i + 4);
  float f[8] = {a.x, a.y, a.z, a.w, b.x, b.y, b.z, b.w};
  *(uint4*)(o + i) = pack8(f);
}

// Wt[mat][n][k] = bf16(W[mat][k][n]); mat = layer*2 + (0:W1,1:W2)
__global__ __launch_bounds__(128) void k_wprep(const float* __restrict__ W1,
                                               const float* __restrict__ W2,
                                               unsigned short* __restrict__ Wt) {
  int m = blockIdx.x;
  int n = blockIdx.y;
  int k = threadIdx.x;
  int l = m >> 1, s = m & 1;
  const float* W = (s == 0 ? W1 : W2) + (size_t)l * D * D;
  Wt[((size_t)m * D + n) * D + k] = f2bf(W[(size_t)k * D + n]);
}

// ---------------- bucket histogram + scan ----------------
__global__ __launch_bounds__(256) void k_histb(const int* __restrict__ dst,
                                               int* __restrict__ ecount) {
  __shared__ int lh[NBUCK];
  const int t = threadIdx.x;
  const int e0 = blockIdx.x * EPB;
  const int e1 = min(e0 + EPB, N_EDGES);
  for (int i = t; i < NBUCK; i += 256) lh[i] = 0;
  __syncthreads();
  for (int e = e0 + t; e < e1; e += 256) atomicAdd(&lh[dst[e] >> 8], 1);
  __syncthreads();
  for (int i = t; i < NBUCK; i += 256)
    if (lh[i]) atomicAdd(&ecount[i], lh[i]);
}

__global__ __launch_bounds__(512) void k_scanb(const int* __restrict__ ecount,
                                               int* __restrict__ ebase,
                                               int* __restrict__ gcur) {
  __shared__ int ls[512];
  int t = threadIdx.x;
  int v = (t < NBUCK) ? ecount[t] : 0;
  ls[t] = v;
  __syncthreads();
  for (int o = 1; o < 512; o <<= 1) {
    int u = (t >= o) ? ls[t - o] : 0;
    __syncthreads();
    ls[t] += u;
    __syncthreads();
  }
  int ex = ls[t] - v;
  if (t < NBUCK) { ebase[t] = ex; gcur[t] = ex; }
  if (t == 0) ebase[NBUCK] = N_EDGES;
}

// ---------------- two-phase bucketed edge scatter ----------------
__global__ __launch_bounds__(256) void k_scatA(const int* __restrict__ ei,
                                               int* __restrict__ gcur,
                                               int2* __restrict__ pairs) {
  __shared__ int lh[NBUCK];
  __shared__ int lbase[NBUCK];
  const int t = threadIdx.x;
  const int e0 = blockIdx.x * EPB;
  const int e1 = min(e0 + EPB, N_EDGES);
  for (int i = t; i < NBUCK; i += 256) lh[i] = 0;
  __syncthreads();
  for (int e = e0 + t; e < e1; e += 256) atomicAdd(&lh[ei[N_EDGES + e] >> 8], 1);
  __syncthreads();
  for (int i = t; i < NBUCK; i += 256)
    lbase[i] = (lh[i] > 0) ? atomicAdd(&gcur[i], lh[i]) : 0;
  __syncthreads();
  for (int e = e0 + t; e < e1; e += 256) {
    int s = ei[e];
    int d = ei[N_EDGES + e];
    int p = atomicAdd(&lbase[d >> 8], 1);
    pairs[p] = make_int2(s, d);
  }
}

// Phase B: per bucket, build per-node CSR offsets in LDS and place srcs.
// esrc stores BYTE offsets (src * 256) — consumed by k_aggz.
__global__ __launch_bounds__(256) void k_scatB(const int2* __restrict__ pairs,
                                               const int* __restrict__ ebase,
                                               int* __restrict__ off,
                                               int* __restrict__ esrc) {
  __shared__ int lcnt[BNODES];
  __shared__ int ls[256];
  const int t = threadIdx.x;
  const int b = blockIdx.x;
  const int nb0 = b * BNODES;
  const int nn = min(BNODES, N_NODES - nb0);
  const int s0 = ebase[b], s1 = ebase[b + 1];
  if (t < nn) lcnt[t] = 0;
  __syncthreads();
  for (int e = s0 + t; e < s1; e += 256) atomicAdd(&lcnt[pairs[e].y - nb0], 1);
  __syncthreads();
  int c0 = (t < nn) ? lcnt[t] : 0;
  ls[t] = c0;
  __syncthreads();
  for (int o = 1; o < 256; o <<= 1) {
    int u = (t >= o) ? ls[t - o] : 0;
    __syncthreads();
    ls[t] += u;
    __syncthreads();
  }
  int pre = ls[t] - c0;  // exclusive prefix within bucket
  if (t < nn) {
    off[nb0 + t] = s0 + pre;
    lcnt[t] = s0 + pre;  // reuse as cursor
  }
  __syncthreads();
  for (int e = s0 + t; e < s1; e += 256) {
    int2 p = pairs[e];
    int pos = atomicAdd(&lcnt[p.y - nb0], 1);
    esrc[pos] = p.x << 8;  // byte offset of the 256B bf16 row
  }
  if (b == 0 && t == 0) off[N_NODES] = N_EDGES;
}

// ---------------- agg + (1+eps)*h: ONE WAVE PER NODE, 2 feats/lane ----------
// R3-measured-best form (65.4us): 4B/lane, 8-edge unroll; byte-offset esrc.
// At the fabric-BW roofline: 410MB logical / 65us = 6.3 TB/s (R9 measured).
// MODE 1 applies h' = relu(y*sc + tb) to every gathered row on the fly.
template <int MODE>
__global__ __launch_bounds__(256) void k_aggz(const unsigned short* __restrict__ h,
                                              const int* __restrict__ off,
                                              const int* __restrict__ esrcB,
                                              const float* __restrict__ epsp,
                                              const float* __restrict__ sc,
                                              const float* __restrict__ tb,
                                              unsigned short* __restrict__ z) {
  const int lane = threadIdx.x & 63;
  const int n = blockIdx.x * 4 + (threadIdx.x >> 6);
  const int c = lane << 1;
  const int cb = lane << 2;  // byte offset of the 2 shorts
  const char* hb = (const char*)h;
  float S0 = 0.f, S1 = 0.f, T0 = 0.f, T1 = 0.f;
  if (MODE == 1) { S0 = sc[c]; S1 = sc[c + 1]; T0 = tb[c]; T1 = tb[c + 1]; }
  const float e = 1.0f + epsp[0];
  const int o0 = off[n], o1 = off[n + 1];

  float a0, a1;
  {
    unsigned int u = *(const unsigned int*)(hb + (size_t)n * 256 + cb);
    float lo = __uint_as_float(u << 16);
    float hi = __uint_as_float(u & 0xffff0000u);
    if (MODE == 1) {
      lo = fmaxf(fmaf(lo, S0, T0), 0.f);
      hi = fmaxf(fmaf(hi, S1, T1), 0.f);
    }
    a0 = e * lo;
    a1 = e * hi;
  }

  int j = o0;
  for (; j + 7 < o1; j += 8) {
    int b0 = esrcB[j], b1 = esrcB[j + 1], b2 = esrcB[j + 2], b3 = esrcB[j + 3];
    int b4 = esrcB[j + 4], b5 = esrcB[j + 5], b6 = esrcB[j + 6], b7 = esrcB[j + 7];
    unsigned int u0 = *(const unsigned int*)(hb + (unsigned)b0 + cb);
    unsigned int u1 = *(const unsigned int*)(hb + (unsigned)b1 + cb);
    unsigned int u2 = *(const unsigned int*)(hb + (unsigned)b2 + cb);
    unsigned int u3 = *(const unsigned int*)(hb + (unsigned)b3 + cb);
    unsigned int u4 = *(const unsigned int*)(hb + (unsigned)b4 + cb);
    unsigned int u5 = *(const unsigned int*)(hb + (unsigned)b5 + cb);
    unsigned int u6 = *(const unsigned int*)(hb + (unsigned)b6 + cb);
    unsigned int u7 = *(const unsigned int*)(hb + (unsigned)b7 + cb);
    float l0 = __uint_as_float(u0 << 16), h0 = __uint_as_float(u0 & 0xffff0000u);
    float l1 = __uint_as_float(u1 << 16), h1 = __uint_as_float(u1 & 0xffff0000u);
    float l2 = __uint_as_float(u2 << 16), h2 = __uint_as_float(u2 & 0xffff0000u);
    float l3 = __uint_as_float(u3 << 16), h3 = __uint_as_float(u3 & 0xffff0000u);
    float l4 = __uint_as_float(u4 << 16), h4 = __uint_as_float(u4 & 0xffff0000u);
    float l5 = __uint_as_float(u5 << 16), h5 = __uint_as_float(u5 & 0xffff0000u);
    float l6 = __uint_as_float(u6 << 16), h6 = __uint_as_float(u6 & 0xffff0000u);
    float l7 = __uint_as_float(u7 << 16), h7 = __uint_as_float(u7 & 0xffff0000u);
    if (MODE == 1) {
      l0 = fmaxf(fmaf(l0, S0, T0), 0.f); h0 = fmaxf(fmaf(h0, S1, T1), 0.f);
      l1 = fmaxf(fmaf(l1, S0, T0), 0.f); h1 = fmaxf(fmaf(h1, S1, T1), 0.f);
      l2 = fmaxf(fmaf(l2, S0, T0), 0.f); h2 = fmaxf(fmaf(h2, S1, T1), 0.f);
      l3 = fmaxf(fmaf(l3, S0, T0), 0.f); h3 = fmaxf(fmaf(h3, S1, T1), 0.f);
      l4 = fmaxf(fmaf(l4, S0, T0), 0.f); h4 = fmaxf(fmaf(h4, S1, T1), 0.f);
      l5 = fmaxf(fmaf(l5, S0, T0), 0.f); h5 = fmaxf(fmaf(h5, S1, T1), 0.f);
      l6 = fmaxf(fmaf(l6, S0, T0), 0.f); h6 = fmaxf(fmaf(h6, S1, T1), 0.f);
      l7 = fmaxf(fmaf(l7, S0, T0), 0.f); h7 = fmaxf(fmaf(h7, S1, T1), 0.f);
    }
    a0 += ((l0 + l1) + (l2 + l3)) + ((l4 + l5) + (l6 + l7));
    a1 += ((h0 + h1) + (h2 + h3)) + ((h4 + h5) + (h6 + h7));
  }
  for (; j + 3 < o1; j += 4) {
    int b0 = esrcB[j], b1 = esrcB[j + 1], b2 = esrcB[j + 2], b3 = esrcB[j + 3];
    unsigned int u0 = *(const unsigned int*)(hb + (unsigned)b0 + cb);
    unsigned int u1 = *(const unsigned int*)(hb + (unsigned)b1 + cb);
    unsigned int u2 = *(const unsigned int*)(hb + (unsigned)b2 + cb);
    unsigned int u3 = *(const unsigned int*)(hb + (unsigned)b3 + cb);
    float l0 = __uint_as_float(u0 << 16), h0 = __uint_as_float(u0 & 0xffff0000u);
    float l1 = __uint_as_float(u1 << 16), h1 = __uint_as_float(u1 & 0xffff0000u);
    float l2 = __uint_as_float(u2 << 16), h2 = __uint_as_float(u2 & 0xffff0000u);
    float l3 = __uint_as_float(u3 << 16), h3 = __uint_as_float(u3 & 0xffff0000u);
    if (MODE == 1) {
      l0 = fmaxf(fmaf(l0, S0, T0), 0.f); h0 = fmaxf(fmaf(h0, S1, T1), 0.f);
      l1 = fmaxf(fmaf(l1, S0, T0), 0.f); h1 = fmaxf(fmaf(h1, S1, T1), 0.f);
      l2 = fmaxf(fmaf(l2, S0, T0), 0.f); h2 = fmaxf(fmaf(h2, S1, T1), 0.f);
      l3 = fmaxf(fmaf(l3, S0, T0), 0.f); h3 = fmaxf(fmaf(h3, S1, T1), 0.f);
    }
    a0 += (l0 + l1) + (l2 + l3);
    a1 += (h0 + h1) + (h2 + h3);
  }
  for (; j < o1; j++) {
    unsigned int u0 = *(const unsigned int*)(hb + (unsigned)esrcB[j] + cb);
    float l0 = __uint_as_float(u0 << 16), h0 = __uint_as_float(u0 & 0xffff0000u);
    if (MODE == 1) {
      l0 = fmaxf(fmaf(l0, S0, T0), 0.f);
      h0 = fmaxf(fmaf(h0, S1, T1), 0.f);
    }
    a0 += l0;
    a1 += h0;
  }
  unsigned int pk = (unsigned int)f2bf(a0) | ((unsigned int)f2bf(a1) << 16);
  *(unsigned int*)((char*)z + (size_t)n * 256 + cb) = pk;
}

// ---------------- MFMA GEMM + fused BN column stats ----------------
// R9 geometry (64 rows/block, 256 thr, Ws in LDS — measured best 617.7us).
// NEW: C-store via in-LDS transpose WITH AN EXPLICIT __syncthreads() between
// the b16 scatter and the b128 readback. (R10's barrier-less version raced:
// the compiler's aliasing model omits the lgkmcnt dependency between
// short-writes and uint4-reads of the same LDS.) Readback stores are fully
// coalesced uint4 (4 VMEM insts/thread vs 32 scalar 2B stores). Zs stripes
// are wave-private on BOTH the MFMA-read side and the scatter-write side,
// so no cross-wave hazard precedes the barrier.
// MODE=1: A-rows transformed by relu(bn(.)) with coefs folded inline.
template <int MODE>
__global__ __launch_bounds__(256) void k_gemm(const unsigned short* __restrict__ A,
                                              const unsigned short* __restrict__ Wt,
                                              unsigned short* __restrict__ out,
                                              const float* __restrict__ psA,
                                              const float* __restrict__ pqA,
                                              const float* __restrict__ gamA,
                                              const float* __restrict__ betA,
                                              float* __restrict__ ssum,
                                              float* __restrict__ ssq) {
  __shared__ unsigned short Zs[64 * 136];
  __shared__ unsigned short Ws[128 * 136];
  __shared__ float scL[128];
  __shared__ float tbL[128];
  const int t = threadIdx.x;
  const int row0 = blockIdx.x * 64;

  // stage Wt first: loads independent of the BN fold -> overlap latency
#pragma unroll
  for (int i = 0; i < 8; i++) {
    int q = t + i * 256;  // 0..2047: 128 rows x 16 col-blocks
    int r = q >> 4, cbw = (q & 15) << 3;
    *(uint4*)&Ws[r * 136 + cbw] = *(const uint4*)(Wt + (size_t)r * D + cbw);
  }

  if constexpr (MODE == 1) {
    if (t < 128) {
      float S = 0.f, Q = 0.f;
#pragma unroll
      for (int i = 0; i < NSLICE; i++) { S += psA[i * 128 + t]; Q += pqA[i * 128 + t]; }
      float m = S * (1.0f / (float)N_NODES);
      float v = Q * (1.0f / (float)N_NODES) - m * m;
      float r = rsqrtf(v + BN_EPS);
      float s = r * gamA[t];
      scL[t] = s;
      tbL[t] = betA[t] - m * s;
    }
    __syncthreads();  // scL/tbL ready before A transform
  }

#pragma unroll
  for (int i = 0; i < 4; i++) {
    int q = t + i * 256;  // 0..1023: 64 rows x 16 col-blocks
    int r = q >> 4, cb = (q & 15) << 3;
    int grow = row0 + r;
    uint4 u = make_uint4(0u, 0u, 0u, 0u);
    if (grow < N_NODES) {
      u = *(const uint4*)(A + (size_t)grow * D + cb);
      if constexpr (MODE == 1) {
        float f[8];
        unpack8(u, f);
#pragma unroll
        for (int jj = 0; jj < 8; jj++)
          f[jj] = fmaxf(fmaf(f[jj], scL[cb + jj], tbL[cb + jj]), 0.f);
        u = pack8(f);
      }
    }
    *(uint4*)&Zs[r * 136 + cb] = u;
  }
  __syncthreads();

  const int lane = t & 63;
  const int wave = t >> 6;       // 0..3
  const int quad = lane >> 4;
  const int lr = lane & 15;
  const int m0 = wave * 16;      // wave's private 16-row stripe

  f32x4 acc[8];
#pragma unroll
  for (int i = 0; i < 8; i++) acc[i] = (f32x4){0.f, 0.f, 0.f, 0.f};

#pragma unroll
  for (int kc = 0; kc < 128; kc += 32) {
    short8 af = *(const short8*)&Zs[(m0 + lr) * 136 + kc + quad * 8];
#pragma unroll
    for (int nt = 0; nt < 8; nt++) {
      short8 bf = *(const short8*)&Ws[(nt * 16 + lr) * 136 + kc + quad * 8];
      acc[nt] = __builtin_amdgcn_mfma_f32_16x16x32_bf16(af, bf, acc[nt], 0, 0, 0);
    }
  }

  // column stats: per-quad sums -> cross-quad shfl reduce -> direct atomics
  const int slice = blockIdx.x & (NSLICE - 1);
#pragma unroll
  for (int nt = 0; nt < 8; nt++) {
    float s = acc[nt][0] + acc[nt][1] + acc[nt][2] + acc[nt][3];
    float qq = acc[nt][0] * acc[nt][0] + acc[nt][1] * acc[nt][1] +
               acc[nt][2] * acc[nt][2] + acc[nt][3] * acc[nt][3];
    s += __shfl_xor(s, 16);
    s += __shfl_xor(s, 32);
    qq += __shfl_xor(qq, 16);
    qq += __shfl_xor(qq, 32);
    if (quad == 0) {
      atomicAdd(&ssum[slice * 128 + nt * 16 + lr], s);
      atomicAdd(&ssq[slice * 128 + nt * 16 + lr], qq);
    }
  }

  // C-store: scatter acc (bf16) into the wave's OWN Zs stripe, barrier,
  // then coalesced uint4 readback-stores. acc depends on the Zs reads, so
  // the scatter cannot be hoisted above them; the barrier orders scatter
  // writes before readback reads (lgkmcnt(0) + visibility).
#pragma unroll
  for (int nt = 0; nt < 8; nt++) {
#pragma unroll
    for (int rr = 0; rr < 4; rr++) {
      Zs[(m0 + quad * 4 + rr) * 136 + nt * 16 + lr] = f2bf(acc[nt][rr]);
    }
  }
  __syncthreads();
#pragma unroll
  for (int i = 0; i < 4; i++) {
    int idx = lane + i * 64;        // 0..255: 16 rows x 16 col-blocks
    int r = idx >> 4, cb = (idx & 15) << 3;
    int grow = row0 + m0 + r;
    if (grow < N_NODES) {
      *(uint4*)(out + (size_t)grow * D + cb) = *(const uint4*)&Zs[(m0 + r) * 136 + cb];
    }
  }
}

// fold stats -> affine BN coeffs: bn(y) = y*sc + tb (for the 25000-block aggz
// consumer; 1-block launch is ~3us — NEVER a per-block __threadfence fold,
// which forces cross-XCD L2 writebacks (~220us, measured round 4))
__global__ void k_bnfin(const float* __restrict__ ssum, const float* __restrict__ ssq,
                        const float* __restrict__ gamma, const float* __restrict__ beta,
                        float* __restrict__ sc, float* __restrict__ tb) {
  int f = threadIdx.x;
  float S = 0.f, Q = 0.f;
  for (int i = 0; i < NSLICE; i++) { S += ssum[i * 128 + f]; Q += ssq[i * 128 + f]; }
  float m = S * (1.0f / (float)N_NODES);
  float v = Q * (1.0f / (float)N_NODES) - m * m;
  float r = rsqrtf(v + BN_EPS);
  float s = r * gamma[f];
  sc[f] = s;
  tb[f] = beta[f] - m * s;
}

// ---------------- fused BN2+ReLU + node_emb write + graph readout ------------
#define RCH 64
__global__ __launch_bounds__(128) void k_readout(const unsigned short* __restrict__ y,
                                                 const int* __restrict__ batch,
                                                 const float* __restrict__ psA,
                                                 const float* __restrict__ pqA,
                                                 const float* __restrict__ gam,
                                                 const float* __restrict__ bet,
                                                 float* __restrict__ node_out,
                                                 float* __restrict__ gsum,
                                                 int* __restrict__ gcnt) {
  int start = blockIdx.x * RCH;
  int end = min(start + RCH, N_NODES);
  if (start >= end) return;
  int f = threadIdx.x;
  // inline BN-coef fold
  float S = 0.f, Q = 0.f;
#pragma unroll
  for (int i = 0; i < NSLICE; i++) { S += psA[i * 128 + f]; Q += pqA[i * 128 + f]; }
  float m = S * (1.0f / (float)N_NODES);
  float v = Q * (1.0f / (float)N_NODES) - m * m;
  float r = rsqrtf(v + BN_EPS);
  float s = r * gam[f];
  float tt = bet[f] - m * s;

  float acc = 0.f;
  int cnt = 0;
  int curg = batch[start];
  for (int n = start; n < end; n++) {
    int gg = batch[n];
    float vv = fmaxf(fmaf(bf2f(y[(size_t)n * D + f]), s, tt), 0.f);
    node_out[(size_t)n * D + f] = vv;
    if (gg != curg) {
      atomicAdd(&gsum[curg * D + f], acc);
      if (f == 0) atomicAdd(&gcnt[curg], cnt);
      acc = 0.f; cnt = 0; curg = gg;
    }
    acc += vv;
    cnt++;
  }
  atomicAdd(&gsum[curg * D + f], acc);
  if (f == 0) atomicAdd(&gcnt[curg], cnt);
}

__global__ __launch_bounds__(128) void k_gnorm(const float* __restrict__ gsum,
                                               const int* __restrict__ gcnt,
                                               float* __restrict__ out) {
  __shared__ float red[128];
  int g = blockIdx.x, f = threadIdx.x;
  float c = (float)gcnt[g];
  float v = gsum[g * D + f] / fmaxf(c, 1.0f);
  red[f] = v * v;
  __syncthreads();
  for (int o = 64; o > 0; o >>= 1) {
    if (f < o) red[f] += red[f + o];
    __syncthreads();
  }
  float nrm = sqrtf(red[0]);
  out[(size_t)g * D + f] = v / fmaxf(nrm, 1e-12f);
}

extern "C" void kernel_launch(void* const* d_in, const int* in_sizes, int n_in,
                              void* d_out, int out_size, void* d_ws, size_t ws_size,
                              hipStream_t stream) {
  const float* x   = (const float*)d_in[0];
  const int*   ei  = (const int*)d_in[1];
  const int*   bat = (const int*)d_in[2];
  const float* W1  = (const float*)d_in[3];
  const float* g1  = (const float*)d_in[4];
  const float* b1  = (const float*)d_in[5];
  const float* W2  = (const float*)d_in[6];
  const float* g2  = (const float*)d_in[7];
  const float* b2  = (const float*)d_in[8];
  const float* eps = (const float*)d_in[9];
  float* out = (float*)d_out;

  char* w = (char*)d_ws;
  const size_t FEAT_B = (size_t)N_NODES * D * 2;
  unsigned short* xb   = (unsigned short*)w; w += FEAT_B;
  unsigned short* bufA = (unsigned short*)w; w += FEAT_B;  // also aliases pairs
  unsigned short* bufB = (unsigned short*)w; w += FEAT_B;
  unsigned short* bufC = (unsigned short*)w; w += FEAT_B;
  unsigned short* WtB  = (unsigned short*)w; w += (size_t)6 * D * D * 2;
  int* off   = (int*)w; w += 400016;
  int* ebase = (int*)w; w += 2048;
  int* gcur  = (int*)w; w += 2048;
  int* esrc  = (int*)w; w += (size_t)N_EDGES * 4;
  float* sc2 = (float*)w; w += 512;
  float* tb2 = (float*)w; w += 512;
  // zero-init region (single memset): ecount | stats | gsum | gcnt
  char* zreg = w;
  int* ecount  = (int*)w; w += 2048;
  float* stats = (float*)w; w += (size_t)6 * 2 * NSLICE * 128 * 4;  // 96 KB
  float* gsum  = (float*)w; w += (size_t)N_GRAPHS * D * 4;
  int* gcnt    = (int*)w; w += 256;
  size_t zbytes = (size_t)((char*)w - zreg);
  // pairs (12.8 MB) aliases bufA (25.6 MB): pairs consumed by k_scatB before
  // the first k_aggz writes bufA (single-stream serialization).
  int2* pairs = (int2*)bufA;

  hipMemsetAsync(zreg, 0, zbytes, stream);

  k_cast<<<(N_NODES * D / 8 + 255) / 256, 256, 0, stream>>>(x, xb);
  k_wprep<<<dim3(6, 128), 128, 0, stream>>>(W1, W2, WtB);

  k_histb<<<NABLK, 256, 0, stream>>>(ei + N_EDGES, ecount);
  k_scanb<<<1, 512, 0, stream>>>(ecount, ebase, gcur);
  k_scatA<<<NABLK, 256, 0, stream>>>(ei, gcur, pairs);
  k_scatB<<<NBUCK, 256, 0, stream>>>(pairs, ebase, off, esrc);

  const int gemm_grid = (N_NODES + 63) / 64;  // 1563
  const int aggz_grid = N_NODES / 4;          // 25000 exactly

  for (int l = 0; l < 3; l++) {
    float* s1 = stats + (size_t)(l * 2 + 0) * 2 * NSLICE * 128;
    float* q1 = s1 + NSLICE * 128;
    float* s2 = stats + (size_t)(l * 2 + 1) * 2 * NSLICE * 128;
    float* q2 = s2 + NSLICE * 128;
    const unsigned short* Wa = WtB + (size_t)(l * 2 + 0) * D * D;
    const unsigned short* Wb = WtB + (size_t)(l * 2 + 1) * D * D;
    if (l == 0) {
      k_aggz<0><<<aggz_grid, 256, 0, stream>>>(xb, off, esrc, eps + l,
                                               nullptr, nullptr, bufA);
    } else {
      k_aggz<1><<<aggz_grid, 256, 0, stream>>>(bufC, off, esrc, eps + l,
                                               sc2, tb2, bufA);
    }
    // y1 = z @ W1 (+ stats)
    k_gemm<0><<<gemm_grid, 256, 0, stream>>>(bufA, Wa, bufB,
                                             nullptr, nullptr, nullptr, nullptr,
                                             s1, q1);
    // y2 = relu(bn1(y1)) @ W2 (+ stats), bn1 coefs folded inline
    k_gemm<1><<<gemm_grid, 256, 0, stream>>>(bufB, Wb, bufC,
                                             s1, q1, g1 + (size_t)l * D, b1 + (size_t)l * D,
                                             s2, q2);
    // bn2 coefs for the next layer's aggz (25000-block consumer: fold once here)
    if (l < 2) {
      k_bnfin<<<1, 128, 0, stream>>>(s2, q2, g2 + (size_t)l * D, b2 + (size_t)l * D,
                                     sc2, tb2);
    }
  }

  float* ps2f = stats + (size_t)(2 * 2 + 1) * 2 * NSLICE * 128;
  float* pq2f = ps2f + NSLICE * 128;
  k_readout<<<(N_NODES + RCH - 1) / RCH, 128, 0, stream>>>(
      bufC, bat, ps2f, pq2f, g2 + (size_t)2 * D, b2 + (size_t)2 * D,
      out, gsum, gcnt);
  k_gnorm<<<N_GRAPHS, 128, 0, stream>>>(gsum, gcnt, out + (size_t)N_NODES * D);
}

// Round 18
// 559.953 us; speedup vs baseline: 1.1154x; 1.0998x over previous
//
#include <hip/hip_runtime.h>

#define N_NODES 100000
#define N_EDGES 1600000
#define D 128
#define N_GRAPHS 64
#define BN_EPS 1e-5f
#define NSLICE 16

// dst-buckets for the two-phase scatter
#define BNODES 256
#define NBUCK ((N_NODES + BNODES - 1) / BNODES)  // 391
#define EPB 8192
#define NABLK ((N_EDGES + EPB - 1) / EPB)        // 196

typedef short short8 __attribute__((ext_vector_type(8)));
typedef float f32x4 __attribute__((ext_vector_type(4)));

__device__ inline unsigned short f2bf(float f) {
  unsigned int u = __float_as_uint(f);
  u += 0x7fffu + ((u >> 16) & 1);
  return (unsigned short)(u >> 16);
}
__device__ inline float bf2f(unsigned short h) {
  return __uint_as_float(((unsigned int)h) << 16);
}
__device__ inline void unpack8(uint4 u, float* f) {
  f[0] = __uint_as_float(u.x << 16); f[1] = __uint_as_float(u.x & 0xffff0000u);
  f[2] = __uint_as_float(u.y << 16); f[3] = __uint_as_float(u.y & 0xffff0000u);
  f[4] = __uint_as_float(u.z << 16); f[5] = __uint_as_float(u.z & 0xffff0000u);
  f[6] = __uint_as_float(u.w << 16); f[7] = __uint_as_float(u.w & 0xffff0000u);
}
__device__ inline uint4 pack8(const float* f) {
  uint4 u;
  u.x = f2bf(f[0]) | ((unsigned)f2bf(f[1]) << 16);
  u.y = f2bf(f[2]) | ((unsigned)f2bf(f[3]) << 16);
  u.z = f2bf(f[4]) | ((unsigned)f2bf(f[5]) << 16);
  u.w = f2bf(f[6]) | ((unsigned)f2bf(f[7]) << 16);
  return u;
}

// ---------------- input casts / weight prep ----------------
__global__ __launch_bounds__(256) void k_cast(const float* __restrict__ in,
                                              unsigned short* __restrict__ o) {
  long i = ((long)blockIdx.x * blockDim.x + threadIdx.x) * 8;
  if (i >= (long)N_NODES * D) return;
  float4 a = *(const float4*)(in + i);
  float4 b = *(const float4*)(in + i + 4);
  float f[8] = {a.x, a.y, a.z, a.w, b.x, b.y, b.z, b.w};
  *(uint4*)(o + i) = pack8(f);
}

// Wt[mat][n][k] = bf16(W[mat][k][n]); mat = layer*2 + (0:W1,1:W2)
__global__ __launch_bounds__(128) void k_wprep(const float* __restrict__ W1,
                                               const float* __restrict__ W2,
                                               unsigned short* __restrict__ Wt) {
  int m = blockIdx.x;
  int n = blockIdx.y;
  int k = threadIdx.x;
  int l = m >> 1, s = m & 1;
  const float* W = (s == 0 ? W1 : W2) + (size_t)l * D * D;
  Wt[((size_t)m * D + n) * D + k] = f2bf(W[(size_t)k * D + n]);
}

// ---------------- bucket histogram + scan ----------------
__global__ __launch_bounds__(256) void k_histb(const int* __restrict__ dst,
                                               int* __restrict__ ecount) {
  __shared__ int lh[NBUCK];
  const int t = threadIdx.x;
  const int e0 = blockIdx.x * EPB;
  const int e1 = min(e0 + EPB, N_EDGES);
  for (int i = t; i < NBUCK; i += 256) lh[i] = 0;
  __syncthreads();
  for (int e = e0 + t; e < e1; e += 256) atomicAdd(&lh[dst[e] >> 8], 1);
  __syncthreads();
  for (int i = t; i < NBUCK; i += 256)
    if (lh[i]) atomicAdd(&ecount[i], lh[i]);
}

__global__ __launch_bounds__(512) void k_scanb(const int* __restrict__ ecount,
                                               int* __restrict__ ebase,
                                               int* __restrict__ gcur) {
  __shared__ int ls[512];
  int t = threadIdx.x;
  int v = (t < NBUCK) ? ecount[t] : 0;
  ls[t] = v;
  __syncthreads();
  for (int o = 1; o < 512; o <<= 1) {
    int u = (t >= o) ? ls[t - o] : 0;
    __syncthreads();
    ls[t] += u;
    __syncthreads();
  }
  int ex = ls[t] - v;
  if (t < NBUCK) { ebase[t] = ex; gcur[t] = ex; }
  if (t == 0) ebase[NBUCK] = N_EDGES;
}

// ---------------- two-phase bucketed edge scatter ----------------
__global__ __launch_bounds__(256) void k_scatA(const int* __restrict__ ei,
                                               int* __restrict__ gcur,
                                               int2* __restrict__ pairs) {
  __shared__ int lh[NBUCK];
  __shared__ int lbase[NBUCK];
  const int t = threadIdx.x;
  const int e0 = blockIdx.x * EPB;
  const int e1 = min(e0 + EPB, N_EDGES);
  for (int i = t; i < NBUCK; i += 256) lh[i] = 0;
  __syncthreads();
  for (int e = e0 + t; e < e1; e += 256) atomicAdd(&lh[ei[N_EDGES + e] >> 8], 1);
  __syncthreads();
  for (int i = t; i < NBUCK; i += 256)
    lbase[i] = (lh[i] > 0) ? atomicAdd(&gcur[i], lh[i]) : 0;
  __syncthreads();
  for (int e = e0 + t; e < e1; e += 256) {
    int s = ei[e];
    int d = ei[N_EDGES + e];
    int p = atomicAdd(&lbase[d >> 8], 1);
    pairs[p] = make_int2(s, d);
  }
}

// Phase B: per bucket, build per-node CSR offsets in LDS and place srcs.
// esrc stores BYTE offsets (src * 256) — consumed by k_aggz.
__global__ __launch_bounds__(256) void k_scatB(const int2* __restrict__ pairs,
                                               const int* __restrict__ ebase,
                                               int* __restrict__ off,
                                               int* __restrict__ esrc) {
  __shared__ int lcnt[BNODES];
  __shared__ int ls[256];
  const int t = threadIdx.x;
  const int b = blockIdx.x;
  const int nb0 = b * BNODES;
  const int nn = min(BNODES, N_NODES - nb0);
  const int s0 = ebase[b], s1 = ebase[b + 1];
  if (t < nn) lcnt[t] = 0;
  __syncthreads();
  for (int e = s0 + t; e < s1; e += 256) atomicAdd(&lcnt[pairs[e].y - nb0], 1);
  __syncthreads();
  int c0 = (t < nn) ? lcnt[t] : 0;
  ls[t] = c0;
  __syncthreads();
  for (int o = 1; o < 256; o <<= 1) {
    int u = (t >= o) ? ls[t - o] : 0;
    __syncthreads();
    ls[t] += u;
    __syncthreads();
  }
  int pre = ls[t] - c0;  // exclusive prefix within bucket
  if (t < nn) {
    off[nb0 + t] = s0 + pre;
    lcnt[t] = s0 + pre;  // reuse as cursor
  }
  __syncthreads();
  for (int e = s0 + t; e < s1; e += 256) {
    int2 p = pairs[e];
    int pos = atomicAdd(&lcnt[p.y - nb0], 1);
    esrc[pos] = p.x << 8;  // byte offset of the 256B bf16 row
  }
  if (b == 0 && t == 0) off[N_NODES] = N_EDGES;
}

// ---------------- agg + (1+eps)*h: ONE WAVE PER NODE, 2 feats/lane ----------
// R3-measured-best form (65.4us): 4B/lane, 8-edge unroll; byte-offset esrc.
// At the fabric-BW roofline: 410MB logical / 65us = 6.3 TB/s (R9 measured).
// MODE 1 applies h' = relu(y*sc + tb) to every gathered row on the fly.
template <int MODE>
__global__ __launch_bounds__(256) void k_aggz(const unsigned short* __restrict__ h,
                                              const int* __restrict__ off,
                                              const int* __restrict__ esrcB,
                                              const float* __restrict__ epsp,
                                              const float* __restrict__ sc,
                                              const float* __restrict__ tb,
                                              unsigned short* __restrict__ z) {
  const int lane = threadIdx.x & 63;
  const int n = blockIdx.x * 4 + (threadIdx.x >> 6);
  const int c = lane << 1;
  const int cb = lane << 2;  // byte offset of the 2 shorts
  const char* hb = (const char*)h;
  float S0 = 0.f, S1 = 0.f, T0 = 0.f, T1 = 0.f;
  if (MODE == 1) { S0 = sc[c]; S1 = sc[c + 1]; T0 = tb[c]; T1 = tb[c + 1]; }
  const float e = 1.0f + epsp[0];
  const int o0 = off[n], o1 = off[n + 1];

  float a0, a1;
  {
    unsigned int u = *(const unsigned int*)(hb + (size_t)n * 256 + cb);
    float lo = __uint_as_float(u << 16);
    float hi = __uint_as_float(u & 0xffff0000u);
    if (MODE == 1) {
      lo = fmaxf(fmaf(lo, S0, T0), 0.f);
      hi = fmaxf(fmaf(hi, S1, T1), 0.f);
    }
    a0 = e * lo;
    a1 = e * hi;
  }

  int j = o0;
  for (; j + 7 < o1; j += 8) {
    int b0 = esrcB[j], b1 = esrcB[j + 1], b2 = esrcB[j + 2], b3 = esrcB[j + 3];
    int b4 = esrcB[j + 4], b5 = esrcB[j + 5], b6 = esrcB[j + 6], b7 = esrcB[j + 7];
    unsigned int u0 = *(const unsigned int*)(hb + (unsigned)b0 + cb);
    unsigned int u1 = *(const unsigned int*)(hb + (unsigned)b1 + cb);
    unsigned int u2 = *(const unsigned int*)(hb + (unsigned)b2 + cb);
    unsigned int u3 = *(const unsigned int*)(hb + (unsigned)b3 + cb);
    unsigned int u4 = *(const unsigned int*)(hb + (unsigned)b4 + cb);
    unsigned int u5 = *(const unsigned int*)(hb + (unsigned)b5 + cb);
    unsigned int u6 = *(const unsigned int*)(hb + (unsigned)b6 + cb);
    unsigned int u7 = *(const unsigned int*)(hb + (unsigned)b7 + cb);
    float l0 = __uint_as_float(u0 << 16), h0 = __uint_as_float(u0 & 0xffff0000u);
    float l1 = __uint_as_float(u1 << 16), h1 = __uint_as_float(u1 & 0xffff0000u);
    float l2 = __uint_as_float(u2 << 16), h2 = __uint_as_float(u2 & 0xffff0000u);
    float l3 = __uint_as_float(u3 << 16), h3 = __uint_as_float(u3 & 0xffff0000u);
    float l4 = __uint_as_float(u4 << 16), h4 = __uint_as_float(u4 & 0xffff0000u);
    float l5 = __uint_as_float(u5 << 16), h5 = __uint_as_float(u5 & 0xffff0000u);
    float l6 = __uint_as_float(u6 << 16), h6 = __uint_as_float(u6 & 0xffff0000u);
    float l7 = __uint_as_float(u7 << 16), h7 = __uint_as_float(u7 & 0xffff0000u);
    if (MODE == 1) {
      l0 = fmaxf(fmaf(l0, S0, T0), 0.f); h0 = fmaxf(fmaf(h0, S1, T1), 0.f);
      l1 = fmaxf(fmaf(l1, S0, T0), 0.f); h1 = fmaxf(fmaf(h1, S1, T1), 0.f);
      l2 = fmaxf(fmaf(l2, S0, T0), 0.f); h2 = fmaxf(fmaf(h2, S1, T1), 0.f);
      l3 = fmaxf(fmaf(l3, S0, T0), 0.f); h3 = fmaxf(fmaf(h3, S1, T1), 0.f);
      l4 = fmaxf(fmaf(l4, S0, T0), 0.f); h4 = fmaxf(fmaf(h4, S1, T1), 0.f);
      l5 = fmaxf(fmaf(l5, S0, T0), 0.f); h5 = fmaxf(fmaf(h5, S1, T1), 0.f);
      l6 = fmaxf(fmaf(l6, S0, T0), 0.f); h6 = fmaxf(fmaf(h6, S1, T1), 0.f);
      l7 = fmaxf(fmaf(l7, S0, T0), 0.f); h7 = fmaxf(fmaf(h7, S1, T1), 0.f);
    }
    a0 += ((l0 + l1) + (l2 + l3)) + ((l4 + l5) + (l6 + l7));
    a1 += ((h0 + h1) + (h2 + h3)) + ((h4 + h5) + (h6 + h7));
  }
  for (; j + 3 < o1; j += 4) {
    int b0 = esrcB[j], b1 = esrcB[j + 1], b2 = esrcB[j + 2], b3 = esrcB[j + 3];
    unsigned int u0 = *(const unsigned int*)(hb + (unsigned)b0 + cb);
    unsigned int u1 = *(const unsigned int*)(hb + (unsigned)b1 + cb);
    unsigned int u2 = *(const unsigned int*)(hb + (unsigned)b2 + cb);
    unsigned int u3 = *(const unsigned int*)(hb + (unsigned)b3 + cb);
    float l0 = __uint_as_float(u0 << 16), h0 = __uint_as_float(u0 & 0xffff0000u);
    float l1 = __uint_as_float(u1 << 16), h1 = __uint_as_float(u1 & 0xffff0000u);
    float l2 = __uint_as_float(u2 << 16), h2 = __uint_as_float(u2 & 0xffff0000u);
    float l3 = __uint_as_float(u3 << 16), h3 = __uint_as_float(u3 & 0xffff0000u);
    if (MODE == 1) {
      l0 = fmaxf(fmaf(l0, S0, T0), 0.f); h0 = fmaxf(fmaf(h0, S1, T1), 0.f);
      l1 = fmaxf(fmaf(l1, S0, T0), 0.f); h1 = fmaxf(fmaf(h1, S1, T1), 0.f);
      l2 = fmaxf(fmaf(l2, S0, T0), 0.f); h2 = fmaxf(fmaf(h2, S1, T1), 0.f);
      l3 = fmaxf(fmaf(l3, S0, T0), 0.f); h3 = fmaxf(fmaf(h3, S1, T1), 0.f);
    }
    a0 += (l0 + l1) + (l2 + l3);
    a1 += (h0 + h1) + (h2 + h3);
  }
  for (; j < o1; j++) {
    unsigned int u0 = *(const unsigned int*)(hb + (unsigned)esrcB[j] + cb);
    float l0 = __uint_as_float(u0 << 16), h0 = __uint_as_float(u0 & 0xffff0000u);
    if (MODE == 1) {
      l0 = fmaxf(fmaf(l0, S0, T0), 0.f);
      h0 = fmaxf(fmaf(h0, S1, T1), 0.f);
    }
    a0 += l0;
    a1 += h0;
  }
  unsigned int pk = (unsigned int)f2bf(a0) | ((unsigned int)f2bf(a1) << 16);
  *(unsigned int*)((char*)z + (size_t)n * 256 + cb) = pk;
}

// ---------------- MFMA GEMM + fused BN column stats ----------------
// R16 base (64 rows/block, Ws in LDS, barrier'd coalesced C-store) +
// RESTORED per-block LDS stats reduction (R3 pattern): quad-0 lanes park
// per-wave column partials in psumL/psqL, the existing C-store barrier
// orders them, then 128 threads reduce 4 waves -> ONE atomicAdd per col
// per array. Cuts stats atomics 4x (1024 -> 256 per block; per-address
// chains 392 -> 98) — isolates the atomic-contention theory for the
// gemm's ~60us-vs-~10us-roofline gap (Wt-latency, geometry, C-store all
// measured-neutral).
// MODE=1: A-rows transformed by relu(bn(.)) with coefs folded inline.
template <int MODE>
__global__ __launch_bounds__(256) void k_gemm(const unsigned short* __restrict__ A,
                                              const unsigned short* __restrict__ Wt,
                                              unsigned short* __restrict__ out,
                                              const float* __restrict__ psA,
                                              const float* __restrict__ pqA,
                                              const float* __restrict__ gamA,
                                              const float* __restrict__ betA,
                                              float* __restrict__ ssum,
                                              float* __restrict__ ssq) {
  __shared__ unsigned short Zs[64 * 136];
  __shared__ unsigned short Ws[128 * 136];
  __shared__ float psumL[4 * 128];
  __shared__ float psqL[4 * 128];
  __shared__ float scL[128];
  __shared__ float tbL[128];
  const int t = threadIdx.x;
  const int row0 = blockIdx.x * 64;

  // stage Wt first: loads independent of the BN fold -> overlap latency
#pragma unroll
  for (int i = 0; i < 8; i++) {
    int q = t + i * 256;  // 0..2047: 128 rows x 16 col-blocks
    int r = q >> 4, cbw = (q & 15) << 3;
    *(uint4*)&Ws[r * 136 + cbw] = *(const uint4*)(Wt + (size_t)r * D + cbw);
  }

  if constexpr (MODE == 1) {
    if (t < 128) {
      float S = 0.f, Q = 0.f;
#pragma unroll
      for (int i = 0; i < NSLICE; i++) { S += psA[i * 128 + t]; Q += pqA[i * 128 + t]; }
      float m = S * (1.0f / (float)N_NODES);
      float v = Q * (1.0f / (float)N_NODES) - m * m;
      float r = rsqrtf(v + BN_EPS);
      float s = r * gamA[t];
      scL[t] = s;
      tbL[t] = betA[t] - m * s;
    }
    __syncthreads();  // scL/tbL ready before A transform
  }

#pragma unroll
  for (int i = 0; i < 4; i++) {
    int q = t + i * 256;  // 0..1023: 64 rows x 16 col-blocks
    int r = q >> 4, cb = (q & 15) << 3;
    int grow = row0 + r;
    uint4 u = make_uint4(0u, 0u, 0u, 0u);
    if (grow < N_NODES) {
      u = *(const uint4*)(A + (size_t)grow * D + cb);
      if constexpr (MODE == 1) {
        float f[8];
        unpack8(u, f);
#pragma unroll
        for (int jj = 0; jj < 8; jj++)
          f[jj] = fmaxf(fmaf(f[jj], scL[cb + jj], tbL[cb + jj]), 0.f);
        u = pack8(f);
      }
    }
    *(uint4*)&Zs[r * 136 + cb] = u;
  }
  __syncthreads();

  const int lane = t & 63;
  const int wave = t >> 6;       // 0..3
  const int quad = lane >> 4;
  const int lr = lane & 15;
  const int m0 = wave * 16;      // wave's private 16-row stripe

  f32x4 acc[8];
#pragma unroll
  for (int i = 0; i < 8; i++) acc[i] = (f32x4){0.f, 0.f, 0.f, 0.f};

#pragma unroll
  for (int kc = 0; kc < 128; kc += 32) {
    short8 af = *(const short8*)&Zs[(m0 + lr) * 136 + kc + quad * 8];
#pragma unroll
    for (int nt = 0; nt < 8; nt++) {
      short8 bf = *(const short8*)&Ws[(nt * 16 + lr) * 136 + kc + quad * 8];
      acc[nt] = __builtin_amdgcn_mfma_f32_16x16x32_bf16(af, bf, acc[nt], 0, 0, 0);
    }
  }

  // column stats: per-quad sums -> cross-quad shfl reduce -> per-wave LDS
#pragma unroll
  for (int nt = 0; nt < 8; nt++) {
    float s = acc[nt][0] + acc[nt][1] + acc[nt][2] + acc[nt][3];
    float qq = acc[nt][0] * acc[nt][0] + acc[nt][1] * acc[nt][1] +
               acc[nt][2] * acc[nt][2] + acc[nt][3] * acc[nt][3];
    s += __shfl_xor(s, 16);
    s += __shfl_xor(s, 32);
    qq += __shfl_xor(qq, 16);
    qq += __shfl_xor(qq, 32);
    if (quad == 0) {
      psumL[wave * 128 + nt * 16 + lr] = s;
      psqL[wave * 128 + nt * 16 + lr] = qq;
    }
  }

  // C-store: scatter acc (bf16) into the wave's OWN Zs stripe; the barrier
  // below orders BOTH the scatter (for the b128 readback) and psumL/psqL
  // (for the cross-wave stats reduction). R10 lesson: never rely on
  // barrier-less mixed-width LDS RAW ordering.
#pragma unroll
  for (int nt = 0; nt < 8; nt++) {
#pragma unroll
    for (int rr = 0; rr < 4; rr++) {
      Zs[(m0 + quad * 4 + rr) * 136 + nt * 16 + lr] = f2bf(acc[nt][rr]);
    }
  }
  __syncthreads();
#pragma unroll
  for (int i = 0; i < 4; i++) {
    int idx = lane + i * 64;        // 0..255: 16 rows x 16 col-blocks
    int r = idx >> 4, cb = (idx & 15) << 3;
    int grow = row0 + m0 + r;
    if (grow < N_NODES) {
      *(uint4*)(out + (size_t)grow * D + cb) = *(const uint4*)&Zs[(m0 + r) * 136 + cb];
    }
  }
  // per-block stats fold: 4 waves -> 1 atomic per column per array
  if (t < 128) {
    float S = psumL[t] + psumL[128 + t] + psumL[256 + t] + psumL[384 + t];
    float Q = psqL[t] + psqL[128 + t] + psqL[256 + t] + psqL[384 + t];
    int slice = blockIdx.x & (NSLICE - 1);
    atomicAdd(&ssum[slice * 128 + t], S);
    atomicAdd(&ssq[slice * 128 + t], Q);
  }
}

// fold stats -> affine BN coeffs: bn(y) = y*sc + tb (for the 25000-block aggz
// consumer; 1-block launch is ~3us — NEVER a per-block __threadfence fold,
// which forces cross-XCD L2 writebacks (~220us, measured round 4))
__global__ void k_bnfin(const float* __restrict__ ssum, const float* __restrict__ ssq,
                        const float* __restrict__ gamma, const float* __restrict__ beta,
                        float* __restrict__ sc, float* __restrict__ tb) {
  int f = threadIdx.x;
  float S = 0.f, Q = 0.f;
  for (int i = 0; i < NSLICE; i++) { S += ssum[i * 128 + f]; Q += ssq[i * 128 + f]; }
  float m = S * (1.0f / (float)N_NODES);
  float v = Q * (1.0f / (float)N_NODES) - m * m;
  float r = rsqrtf(v + BN_EPS);
  float s = r * gamma[f];
  sc[f] = s;
  tb[f] = beta[f] - m * s;
}

// ---------------- fused BN2+ReLU + node_emb write + graph readout ------------
#define RCH 64
__global__ __launch_bounds__(128) void k_readout(const unsigned short* __restrict__ y,
                                                 const int* __restrict__ batch,
                                                 const float* __restrict__ psA,
                                                 const float* __restrict__ pqA,
                                                 const float* __restrict__ gam,
                                                 const float* __restrict__ bet,
                                                 float* __restrict__ node_out,
                                                 float* __restrict__ gsum,
                                                 int* __restrict__ gcnt) {
  int start = blockIdx.x * RCH;
  int end = min(start + RCH, N_NODES);
  if (start >= end) return;
  int f = threadIdx.x;
  // inline BN-coef fold
  float S = 0.f, Q = 0.f;
#pragma unroll
  for (int i = 0; i < NSLICE; i++) { S += psA[i * 128 + f]; Q += pqA[i * 128 + f]; }
  float m = S * (1.0f / (float)N_NODES);
  float v = Q * (1.0f / (float)N_NODES) - m * m;
  float r = rsqrtf(v + BN_EPS);
  float s = r * gam[f];
  float tt = bet[f] - m * s;

  float acc = 0.f;
  int cnt = 0;
  int curg = batch[start];
  for (int n = start; n < end; n++) {
    int gg = batch[n];
    float vv = fmaxf(fmaf(bf2f(y[(size_t)n * D + f]), s, tt), 0.f);
    node_out[(size_t)n * D + f] = vv;
    if (gg != curg) {
      atomicAdd(&gsum[curg * D + f], acc);
      if (f == 0) atomicAdd(&gcnt[curg], cnt);
      acc = 0.f; cnt = 0; curg = gg;
    }
    acc += vv;
    cnt++;
  }
  atomicAdd(&gsum[curg * D + f], acc);
  if (f == 0) atomicAdd(&gcnt[curg], cnt);
}

__global__ __launch_bounds__(128) void k_gnorm(const float* __restrict__ gsum,
                                               const int* __restrict__ gcnt,
                                               float* __restrict__ out) {
  __shared__ float red[128];
  int g = blockIdx.x, f = threadIdx.x;
  float c = (float)gcnt[g];
  float v = gsum[g * D + f] / fmaxf(c, 1.0f);
  red[f] = v * v;
  __syncthreads();
  for (int o = 64; o > 0; o >>= 1) {
    if (f < o) red[f] += red[f + o];
    __syncthreads();
  }
  float nrm = sqrtf(red[0]);
  out[(size_t)g * D + f] = v / fmaxf(nrm, 1e-12f);
}

extern "C" void kernel_launch(void* const* d_in, const int* in_sizes, int n_in,
                              void* d_out, int out_size, void* d_ws, size_t ws_size,
                              hipStream_t stream) {
  const float* x   = (const float*)d_in[0];
  const int*   ei  = (const int*)d_in[1];
  const int*   bat = (const int*)d_in[2];
  const float* W1  = (const float*)d_in[3];
  const float* g1  = (const float*)d_in[4];
  const float* b1  = (const float*)d_in[5];
  const float* W2  = (const float*)d_in[6];
  const float* g2  = (const float*)d_in[7];
  const float* b2  = (const float*)d_in[8];
  const float* eps = (const float*)d_in[9];
  float* out = (float*)d_out;

  char* w = (char*)d_ws;
  const size_t FEAT_B = (size_t)N_NODES * D * 2;
  unsigned short* xb   = (unsigned short*)w; w += FEAT_B;
  unsigned short* bufA = (unsigned short*)w; w += FEAT_B;  // also aliases pairs
  unsigned short* bufB = (unsigned short*)w; w += FEAT_B;
  unsigned short* bufC = (unsigned short*)w; w += FEAT_B;
  unsigned short* WtB  = (unsigned short*)w; w += (size_t)6 * D * D * 2;
  int* off   = (int*)w; w += 400016;
  int* ebase = (int*)w; w += 2048;
  int* gcur  = (int*)w; w += 2048;
  int* esrc  = (int*)w; w += (size_t)N_EDGES * 4;
  float* sc2 = (float*)w; w += 512;
  float* tb2 = (float*)w; w += 512;
  // zero-init region (single memset): ecount | stats | gsum | gcnt
  char* zreg = w;
  int* ecount  = (int*)w; w += 2048;
  float* stats = (float*)w; w += (size_t)6 * 2 * NSLICE * 128 * 4;  // 96 KB
  float* gsum  = (float*)w; w += (size_t)N_GRAPHS * D * 4;
  int* gcnt    = (int*)w; w += 256;
  size_t zbytes = (size_t)((char*)w - zreg);
  // pairs (12.8 MB) aliases bufA (25.6 MB): pairs consumed by k_scatB before
  // the first k_aggz writes bufA (single-stream serialization).
  int2* pairs = (int2*)bufA;

  hipMemsetAsync(zreg, 0, zbytes, stream);

  k_cast<<<(N_NODES * D / 8 + 255) / 256, 256, 0, stream>>>(x, xb);
  k_wprep<<<dim3(6, 128), 128, 0, stream>>>(W1, W2, WtB);

  k_histb<<<NABLK, 256, 0, stream>>>(ei + N_EDGES, ecount);
  k_scanb<<<1, 512, 0, stream>>>(ecount, ebase, gcur);
  k_scatA<<<NABLK, 256, 0, stream>>>(ei, gcur, pairs);
  k_scatB<<<NBUCK, 256, 0, stream>>>(pairs, ebase, off, esrc);

  const int gemm_grid = (N_NODES + 63) / 64;  // 1563
  const int aggz_grid = N_NODES / 4;          // 25000 exactly

  for (int l = 0; l < 3; l++) {
    float* s1 = stats + (size_t)(l * 2 + 0) * 2 * NSLICE * 128;
    float* q1 = s1 + NSLICE * 128;
    float* s2 = stats + (size_t)(l * 2 + 1) * 2 * NSLICE * 128;
    float* q2 = s2 + NSLICE * 128;
    const unsigned short* Wa = WtB + (size_t)(l * 2 + 0) * D * D;
    const unsigned short* Wb = WtB + (size_t)(l * 2 + 1) * D * D;
    if (l == 0) {
      k_aggz<0><<<aggz_grid, 256, 0, stream>>>(xb, off, esrc, eps + l,
                                               nullptr, nullptr, bufA);
    } else {
      k_aggz<1><<<aggz_grid, 256, 0, stream>>>(bufC, off, esrc, eps + l,
                                               sc2, tb2, bufA);
    }
    // y1 = z @ W1 (+ stats)
    k_gemm<0><<<gemm_grid, 256, 0, stream>>>(bufA, Wa, bufB,
                                             nullptr, nullptr, nullptr, nullptr,
                                             s1, q1);
    // y2 = relu(bn1(y1)) @ W2 (+ stats), bn1 coefs folded inline
    k_gemm<1><<<gemm_grid, 256, 0, stream>>>(bufB, Wb, bufC,
                                             s1, q1, g1 + (size_t)l * D, b1 + (size_t)l * D,
                                             s2, q2);
    // bn2 coefs for the next layer's aggz (25000-block consumer: fold once here)
    if (l < 2) {
      k_bnfin<<<1, 128, 0, stream>>>(s2, q2, g2 + (size_t)l * D, b2 + (size_t)l * D,
                                     sc2, tb2);
    }
  }

  float* ps2f = stats + (size_t)(2 * 2 + 1) * 2 * NSLICE * 128;
  float* pq2f = ps2f + NSLICE * 128;
  k_readout<<<(N_NODES + RCH - 1) / RCH, 128, 0, stream>>>(
      bufC, bat, ps2f, pq2f, g2 + (size_t)2 * D, b2 + (size_t)2 * D,
      out, gsum, gcnt);
  k_gnorm<<<N_GRAPHS, 128, 0, stream>>>(gsum, gcnt, out + (size_t)N_NODES * D);
}